// Round 4
// baseline (258.111 us; speedup 1.0000x reference)
//
#include <hip/hip_runtime.h>

typedef float f32x4 __attribute__((ext_vector_type(4)));

// ---------------------------------------------------------------------------
// Cubic B-spline basis, N_BASIS=7, clamped knots [-1,-1,-1,-1,-.5,0,.5,1,1,1,1]
// Mirrors the reference Cox-de Boor recursion; guards fold at compile time.
// ---------------------------------------------------------------------------
__device__ __forceinline__ void bspline7(float x, float B[7]) {
    constexpr float t[11] = {-1.f, -1.f, -1.f, -1.f, -0.5f, 0.f, 0.5f, 1.f, 1.f, 1.f, 1.f};
    float xe = fminf(fmaxf(x, -1.f), 0.999999f);  // f32(1 - 1e-6)
    float N[10];
#pragma unroll
    for (int i = 0; i < 10; ++i)
        N[i] = (xe >= t[i] && xe < t[i + 1]) ? 1.f : 0.f;
#pragma unroll
    for (int d = 1; d <= 3; ++d) {
#pragma unroll
        for (int i = 0; i + d < 10; ++i) {
            float ld = t[i + d] - t[i];
            float rd = t[i + d + 1] - t[i + 1];
            float left  = (ld > 0.f) ? (xe - t[i]) / ld * N[i] : 0.f;
            float right = (rd > 0.f) ? (t[i + d + 1] - xe) / rd * N[i + 1] : 0.f;
            N[i] = left + right;
        }
    }
#pragma unroll
    for (int k = 0; k < 7; ++k) B[k] = N[k];
}

// ---------------------------------------------------------------------------
// Geometry
// ---------------------------------------------------------------------------
#define H0 384
#define H1 382
#define H2 380
#define NP2 (H2 * H2)           // 144400
#define L_DENSE (NP2 * 7)       // 1010800 floats per W3 row
#define L4_DENSE (L_DENSE / 4)  // 252700 float4 per W3 row
#define TILE 16                 // v output tile
#define HTILE 18                // h tile (TILE+2)
#define XTILE 20                // x tile (TILE+4)

// ---------------------------------------------------------------------------
// k_fused: x -> conv1 -> basis -> conv2 -> basis -> Bv   (all in LDS)
// One block = 16x16 v-tile. Also zeroes acc32 (ws is poisoned 0xAA).
// ---------------------------------------------------------------------------
__global__ __launch_bounds__(256) void k_fused(const float* __restrict__ x,
                                               const float* __restrict__ W1,
                                               const float* __restrict__ W2,
                                               float* __restrict__ Bv,
                                               float* __restrict__ acc32) {
    __shared__ float w1[378];                       // [2][27][7]
    __shared__ float w2[126];                       // [18][7]
    __shared__ float bx[3 * XTILE * XTILE * 7];     // 8400 floats, 33.6 KB
    __shared__ float bh[2 * HTILE * HTILE * 7];     // 4536 floats, 18.1 KB

    const int tid = threadIdx.x;
    const int i0 = blockIdx.y * TILE;
    const int j0 = blockIdx.x * TILE;

    if (blockIdx.x == 0 && blockIdx.y == 0 && tid < 32) acc32[tid] = 0.f;

    for (int i = tid; i < 378; i += 256) w1[i] = W1[i];
    for (int i = tid; i < 126; i += 256) w2[i] = W2[i];

    // Stage 1: basis of the 20x20x3 x-tile (OOB -> 0, safe: only feeds
    // h-positions that no valid v-pixel consumes).
    for (int t = tid; t < 3 * XTILE * XTILE; t += 256) {
        int c = t / (XTILE * XTILE);
        int r = t % (XTILE * XTILE);
        int ii = r / XTILE, jj = r % XTILE;
        int gi = i0 + ii, gj = j0 + jj;
        float xv = (gi < H0 && gj < H0) ? x[(c * H0 + gi) * H0 + gj] : 0.f;
        float B[7];
        bspline7(xv, B);
#pragma unroll
        for (int k = 0; k < 7; ++k) bx[t * 7 + k] = B[k];
    }
    __syncthreads();

    // Stage 2: conv1 (both channels) + basis -> bh
    for (int t = tid; t < HTILE * HTILE; t += 256) {
        int i1 = t / HTILE, j1 = t % HTILE;
        float acc0 = 0.f, acc1 = 0.f;
#pragma unroll
        for (int c = 0; c < 3; ++c)
#pragma unroll
            for (int di = 0; di < 3; ++di)
#pragma unroll
                for (int dj = 0; dj < 3; ++dj) {
                    const float* b = &bx[(((c * XTILE) + (i1 + di)) * XTILE + (j1 + dj)) * 7];
                    int e = c * 9 + di * 3 + dj;
                    const float* u0 = &w1[e * 7];
                    const float* u1 = &w1[189 + e * 7];
#pragma unroll
                    for (int k = 0; k < 7; ++k) {
                        float bvv = b[k];
                        acc0 += bvv * u0[k];
                        acc1 += bvv * u1[k];
                    }
                }
        float B0[7], B1[7];
        bspline7(acc0, B0);
        bspline7(acc1, B1);
#pragma unroll
        for (int k = 0; k < 7; ++k) {
            bh[t * 7 + k] = B0[k];
            bh[(HTILE * HTILE + t) * 7 + k] = B1[k];
        }
    }
    __syncthreads();

    // Stage 3: conv2 + basis -> Bv (global, layout [p*7+k] matching W3)
    int li = tid / TILE, lj = tid % TILE;
    int gi2 = i0 + li, gj2 = j0 + lj;
    if (gi2 < H2 && gj2 < H2) {
        float acc = 0.f;
#pragma unroll
        for (int c = 0; c < 2; ++c)
#pragma unroll
            for (int di = 0; di < 3; ++di)
#pragma unroll
                for (int dj = 0; dj < 3; ++dj) {
                    const float* b = &bh[((c * HTILE + (li + di)) * HTILE + (lj + dj)) * 7];
                    const float* u = &w2[(c * 9 + di * 3 + dj) * 7];
#pragma unroll
                    for (int k = 0; k < 7; ++k) acc += b[k] * u[k];
                }
        float B[7];
        bspline7(acc, B);
        size_t p = (size_t)gi2 * H2 + gj2;
#pragma unroll
        for (int k = 0; k < 7; ++k) Bv[p * 7 + k] = B[k];
    }
}

// ---------------------------------------------------------------------------
// k_dense1: 32 dot products of length 1,010,800. blockIdx.y = output row o.
// W3 streamed nontemporal (read-once); Bv served from L2/LLC.
// ---------------------------------------------------------------------------
__global__ __launch_bounds__(256) void k_dense1(const float* __restrict__ W3,
                                                const float* __restrict__ Bv,
                                                float* __restrict__ acc32) {
    int o = blockIdx.y;
    const f32x4* w = (const f32x4*)(W3 + (size_t)o * L_DENSE);
    const f32x4* b = (const f32x4*)Bv;
    float s = 0.f;
    for (int f = blockIdx.x * blockDim.x + threadIdx.x; f < L4_DENSE;
         f += gridDim.x * blockDim.x) {
        f32x4 wv = __builtin_nontemporal_load(&w[f]);
        f32x4 bv = b[f];
        s += wv.x * bv.x + wv.y * bv.y + wv.z * bv.z + wv.w * bv.w;
    }
#pragma unroll
    for (int off = 32; off > 0; off >>= 1) s += __shfl_down(s, off, 64);
    __shared__ float red[4];
    if ((threadIdx.x & 63) == 0) red[threadIdx.x >> 6] = s;
    __syncthreads();
    if (threadIdx.x == 0)
        atomicAdd(&acc32[o], red[0] + red[1] + red[2] + red[3]);
}

// k_dense2: (32 -> 10)
__global__ void k_dense2(const float* __restrict__ acc32, const float* __restrict__ W4,
                         float* __restrict__ out) {
    int o = threadIdx.x;
    if (o >= 10) return;
    float s = 0.f;
    for (int e = 0; e < 32; ++e) {
        float B[7];
        bspline7(acc32[e], B);
#pragma unroll
        for (int k = 0; k < 7; ++k) s += B[k] * W4[(o * 32 + e) * 7 + k];
    }
    out[o] = s;
}

extern "C" void kernel_launch(void* const* d_in, const int* in_sizes, int n_in,
                              void* d_out, int out_size, void* d_ws, size_t ws_size,
                              hipStream_t stream) {
    const float* x  = (const float*)d_in[0];   // [1,3,384,384]
    const float* W1 = (const float*)d_in[1];   // [2,27,7]
    const float* W2 = (const float*)d_in[2];   // [1,18,7]
    const float* W3 = (const float*)d_in[3];   // [32,144400,7]
    const float* W4 = (const float*)d_in[4];   // [10,32,7]
    float* out = (float*)d_out;                // [10]

    char* ws = (char*)d_ws;
    float* acc32 = (float*)ws;            // 128 B
    float* Bv = (float*)(ws + 128);       // 4,043,200 B (16B-aligned)

    dim3 gfuse((H2 + TILE - 1) / TILE, (H2 + TILE - 1) / TILE);  // 24x24
    k_fused<<<gfuse, 256, 0, stream>>>(x, W1, W2, Bv, acc32);
    k_dense1<<<dim3(64, 32), 256, 0, stream>>>(W3, Bv, acc32);
    k_dense2<<<1, 64, 0, stream>>>(acc32, W4, out);
}